// Round 15
// baseline (66.031 us; speedup 1.0000x reference)
//
#include <hip/hip_runtime.h>
#include <stdint.h>

#define N_ROWS 65536
#define K_CODES 1024
#define DIM 256

typedef unsigned int uint;

// d_ws layout:
//   [0, 4K)       loss accumulator (first 4B)
//   [4K, 8K)      enS[1024]: ||e||^2 * 32768 + 16384 (scaled+biased fp32)
//   [8K, +128K)   E4: fp4(e2m1) codebook scaled x4096, 128B per code
#define WS_LOSS_OFF  0
#define WS_ENS_OFF   4096
#define WS_E4_OFF    8192

typedef __attribute__((ext_vector_type(4))) float f32x4;
typedef __attribute__((ext_vector_type(4))) int   i32x4;
typedef __attribute__((ext_vector_type(8))) int   i32x8;

// X -> fp8 e4m3 scaled by -16 (negated so MFMA yields enS' - 2x.e directly)
#define XSCALE  (-16.0f)
#define ESCALE4 4096.0f
#define BIAS    16384.0f
#define UNSCALE 3.0517578125e-05f   // 1/32768, exact pow2
#define SCALE1  0x7F7F7F7Fu         // E8M0 identity scales

__device__ __forceinline__ uint pack4_fp8(float a, float b, float c, float d) {
    uint r = 0;
    r = __builtin_amdgcn_cvt_pk_fp8_f32(a, b, r, false);
    r = __builtin_amdgcn_cvt_pk_fp8_f32(c, d, r, true);
    return r;
}
// fp4 e2m1 encode: grid {0,0.5,1,1.5,2,3,4,6}, nearest; input |x|<=4 here
__device__ __forceinline__ uint enc_fp4(float x) {
    float a = fabsf(x);
    uint idx = (a < 0.25f) ? 0u : (a < 0.75f) ? 1u : (a < 1.25f) ? 2u :
               (a < 1.75f) ? 3u : (a < 2.5f)  ? 4u : (a < 3.5f)  ? 5u :
               (a < 5.0f)  ? 6u : 7u;
    return idx | ((x < 0.f) ? 8u : 0u);
}
__device__ __forceinline__ void gload_lds16(const void* g, void* l) {
    __builtin_amdgcn_global_load_lds(
        (const __attribute__((address_space(1))) void*)g,
        (__attribute__((address_space(3))) void*)l, 16, 0, 0);
}

// ---- prep: E -> fp4 codebook (x4096) + scaled/biased norms + zero loss -----
__global__ __launch_bounds__(256) void vq_prep(const float* __restrict__ E,
                                               unsigned char* __restrict__ E4,
                                               float* __restrict__ enS,
                                               float* __restrict__ lossAcc) {
    int id = blockIdx.x * 256 + threadIdx.x;      // 65536 = 1024 codes * 64 f4
    if (id == 0) lossAcc[0] = 0.f;
    int code = id >> 6, c4 = id & 63;
    float4 v = *reinterpret_cast<const float4*>(E + (size_t)code * DIM + c4 * 4);
    uint n0 = enc_fp4(v.x * ESCALE4), n1 = enc_fp4(v.y * ESCALE4);
    uint n2 = enc_fp4(v.z * ESCALE4), n3 = enc_fp4(v.w * ESCALE4);
    uint hw = (n0 | (n1 << 4)) | ((n2 | (n3 << 4)) << 8);
    *reinterpret_cast<unsigned short*>(E4 + (size_t)code * 128 + c4 * 2) =
        (unsigned short)hw;

    float s = v.x * v.x + v.y * v.y + v.z * v.z + v.w * v.w;
    #pragma unroll
    for (int m = 32; m >= 1; m >>= 1) s += __shfl_down(s, m, 64);
    if (c4 == 0) enS[code] = s * 32768.0f + BIAS;
}

// ---- fused main: LDS-RESIDENT fp4 codebook, barrier-free sweep -------------
// Grid 256 = 1 block/CU; block = 512 thr = 8 waves, 256 rows (wave w: rows
// w*32..+31, m=2). The ENTIRE fp4 codebook (128KB) + enS (4KB) is staged into
// LDS once (ONE __syncthreads); the main loop is barrier-free: each wave
// sweeps 64 x 16-code groups (2 ds_read_b128 + 4 MFMA(K=128) + 8 min-fold),
// self-paced -> A/loop/out phases of 8 waves overlap naturally.
// MFMA: A = fp8(-16x), B = fp4(4096e) blgp=4, C-init = enS' so
// acc_out = 32768*(||e||^2 - 2x.e) + 16384; u32-packed argmin fold.
// Codes redistributed via fully-unrolled __shfl (no LDS, no barrier).
__global__ __launch_bounds__(512, 1) void vq_main(const float* __restrict__ X,
                                                  const unsigned char* __restrict__ E4,
                                                  const float* __restrict__ enS,
                                                  const float* __restrict__ E,
                                                  float* __restrict__ out,
                                                  float* __restrict__ lossAcc) {
    __shared__ __align__(16) unsigned char cbL[131072];   // full fp4 codebook
    __shared__ __align__(16) float enSLds[1024];

    const int tid = threadIdx.x;
    const int lane = tid & 63;
    const int w = tid >> 6;          // wave 0..7
    const int cl = lane & 15;
    const int kq = lane >> 4;
    const int row0 = blockIdx.x * 256;
    const int key = (cl & 7) << 4;   // read-side XOR swizzle

    // ---- one-time codebook stage: 128KB, 16 x 16B per thread --------------
    #pragma unroll
    for (int j = 0; j < 16; ++j) {
        int o = j * 8192 + tid * 16;             // linear LDS dest
        int rr = o >> 7;                         // code row (0..1023)
        int cb = (o & 127) ^ ((rr & 7) << 4);    // pre-swizzled source (rule 21)
        gload_lds16(E4 + (size_t)rr * 128 + cb, cbL + o);
    }
    if (tid < 256)
        reinterpret_cast<f32x4*>(enSLds)[tid] =
            reinterpret_cast<const f32x4*>(enS)[tid];

    // ---- A phase: global -> fp8(-x) regs (m=2, K=128 frags) + x^2 partial --
    i32x8 aF[2][2];
    float xsum = 0.f;
    #pragma unroll
    for (int m = 0; m < 2; ++m) {
        const float* rp = X + (size_t)(row0 + w * 32 + m * 16 + cl) * DIM;
        #pragma unroll
        for (int ks = 0; ks < 2; ++ks) {
            const float* p = rp + ks * 128 + kq * 32;
            uint u[8];
            #pragma unroll
            for (int q = 0; q < 8; ++q) {
                float4 v = *reinterpret_cast<const float4*>(p + q * 4);
                u[q] = pack4_fp8(v.x * XSCALE, v.y * XSCALE,
                                 v.z * XSCALE, v.w * XSCALE);
                xsum = fmaf(v.x, v.x, xsum); xsum = fmaf(v.y, v.y, xsum);
                xsum = fmaf(v.z, v.z, xsum); xsum = fmaf(v.w, v.w, xsum);
            }
            i32x8 f = {(int)u[0], (int)u[1], (int)u[2], (int)u[3],
                       (int)u[4], (int)u[5], (int)u[6], (int)u[7]};
            aF[m][ks] = f;
        }
    }

    __syncthreads();     // single barrier: codebook + enS resident

    uint best[2][4];
    #pragma unroll
    for (int m = 0; m < 2; ++m)
        #pragma unroll
        for (int rr = 0; rr < 4; ++rr) best[m][rr] = 0xFFFFFFFFu;

    // ---- barrier-free sweep of the resident codebook -----------------------
    #pragma unroll 4
    for (int t = 0; t < 64; ++t) {               // 16-code groups
        float en = enSLds[t * 16 + cl];
        const unsigned char* rb = cbL + (size_t)(t * 16 + cl) * 128;
        f32x4 acc0 = {en, en, en, en};
        f32x4 acc1 = acc0;
        #pragma unroll
        for (int ks = 0; ks < 2; ++ks) {
            i32x4 lo = *reinterpret_cast<const i32x4*>(
                rb + ((ks * 64 + kq * 16) ^ key));
            i32x8 bf = __builtin_shufflevector(lo, lo, 0, 1, 2, 3, 0, 1, 2, 3);
            acc0 = __builtin_amdgcn_mfma_scale_f32_16x16x128_f8f6f4(
                aF[0][ks], bf, acc0, 0, 4, 0, SCALE1, 0, SCALE1);
            acc1 = __builtin_amdgcn_mfma_scale_f32_16x16x128_f8f6f4(
                aF[1][ks], bf, acc1, 0, 4, 0, SCALE1, 0, SCALE1);
        }
        // u32-packed fold (codes ascend -> min keeps first occurrence)
        uint codeN = (uint)(t * 16 + cl);
        #pragma unroll
        for (int rr = 0; rr < 4; ++rr) {
            best[0][rr] = min(best[0][rr],
                              (__float_as_uint(acc0[rr]) & 0xFFFFFC00u) | codeN);
            best[1][rr] = min(best[1][rr],
                              (__float_as_uint(acc1[rr]) & 0xFFFFFC00u) | codeN);
        }
    }

    // ---- wave-local epilogue: butterfly reduce across the 16 cl lanes ------
    // C layout (m89): local row = m*16 + kq*4 + rr.
    float minsum = 0.f;
    int bc[2][4];
    #pragma unroll
    for (int m = 0; m < 2; ++m)
        #pragma unroll
        for (int rr = 0; rr < 4; ++rr) {
            uint v = best[m][rr];
            #pragma unroll
            for (int mask = 1; mask < 16; mask <<= 1)
                v = min(v, (uint)__shfl_xor((int)v, mask, 64));
            bc[m][rr] = (int)(v & 1023u);        // all lanes now hold group min
            if (cl == 0)
                minsum += __uint_as_float(v & 0xFFFFFC00u) - BIAS;
        }

    // loss partial: every thread's x^2 + (cl==0 lanes') scaled min-scores
    float v2 = xsum + ((cl == 0) ? minsum * UNSCALE : 0.f);
    #pragma unroll
    for (int mask = 1; mask < 64; mask <<= 1) v2 += __shfl_xor(v2, mask, 64);
    if (lane == 0) atomicAdd(lossAcc, v2);

    // ---- out[row] = E[bc[row]] (== x + (q-x) to ~3e-7), no barrier ---------
    // row i (0..31): m = i>>4, kq = (i>>2)&3, rr = i&3; src lane = kq*16.
    const int wrow = row0 + w * 32;
    #pragma unroll
    for (int i = 0; i < 32; ++i) {
        int code = __shfl(bc[i >> 4][i & 3], ((i >> 2) & 3) << 4, 64);
        f32x4 q = *reinterpret_cast<const f32x4*>(E + (size_t)code * DIM + lane * 4);
        *reinterpret_cast<f32x4*>(out + (size_t)(wrow + i) * DIM + lane * 4) = q;
    }
}

__global__ void vq_finalize(const float* __restrict__ lossAcc,
                            float* __restrict__ out) {
    out[(size_t)N_ROWS * DIM] = 1.25f * lossAcc[0] / (float)((size_t)N_ROWS * DIM);
}

extern "C" void kernel_launch(void* const* d_in, const int* in_sizes, int n_in,
                              void* d_out, int out_size, void* d_ws, size_t ws_size,
                              hipStream_t stream) {
    const float* X = (const float*)d_in[0];
    const float* E = (const float*)d_in[1];
    float* out = (float*)d_out;

    char* ws = (char*)d_ws;
    float* lossAcc = (float*)(ws + WS_LOSS_OFF);
    float* enS = (float*)(ws + WS_ENS_OFF);
    unsigned char* E4 = (unsigned char*)(ws + WS_E4_OFF);

    vq_prep<<<256, 256, 0, stream>>>(E, E4, enS, lossAcc);
    vq_main<<<N_ROWS / 256, 512, 0, stream>>>(X, E4, enS, E, out, lossAcc);
    vq_finalize<<<1, 1, 0, stream>>>(lossAcc, out);
}